// Round 5
// baseline (507.014 us; speedup 1.0000x reference)
//
#include <hip/hip_runtime.h>

#define T_N 1024
#define B_N 64
#define A_N 128
#define TP1 1025
// STOP_IX=0, CONT_IX=1, ABSTRACT_PENALTY=0.5, CONSISTENCY_RATIO=1.0

typedef float f32x4 __attribute__((ext_vector_type(4)));

__device__ __forceinline__ float bcf(int x){ return __builtin_bit_cast(float, x); }
__device__ __forceinline__ int   bci(float x){ return __builtin_bit_cast(int, x); }

// ---- DPP helpers ----
template<int CTRL, int RM>
__device__ __forceinline__ float dpp_add_step(float x){
  int t = __builtin_amdgcn_update_dpp(0, bci(x), CTRL, RM, 0xf, true);
  return x + bcf(t);
}
__device__ __forceinline__ float wave_sum64(float x){
  x = dpp_add_step<0x111,0xf>(x);   // row_shr:1
  x = dpp_add_step<0x112,0xf>(x);   // row_shr:2
  x = dpp_add_step<0x114,0xf>(x);   // row_shr:4
  x = dpp_add_step<0x118,0xf>(x);   // row_shr:8
  x = dpp_add_step<0x142,0xa>(x);   // row_bcast15
  x = dpp_add_step<0x143,0xc>(x);   // row_bcast31; lane63 = total
  return bcf(__builtin_amdgcn_readlane(bci(x), 63));
}
// four interleaved reductions: ~1 chain latency for 4 sums
__device__ __forceinline__ void wave_sum64_x4(float a, float b, float c, float d,
                                              float& ra, float& rb, float& rc, float& rd){
  a = dpp_add_step<0x111,0xf>(a); b = dpp_add_step<0x111,0xf>(b);
  c = dpp_add_step<0x111,0xf>(c); d = dpp_add_step<0x111,0xf>(d);
  a = dpp_add_step<0x112,0xf>(a); b = dpp_add_step<0x112,0xf>(b);
  c = dpp_add_step<0x112,0xf>(c); d = dpp_add_step<0x112,0xf>(d);
  a = dpp_add_step<0x114,0xf>(a); b = dpp_add_step<0x114,0xf>(b);
  c = dpp_add_step<0x114,0xf>(c); d = dpp_add_step<0x114,0xf>(d);
  a = dpp_add_step<0x118,0xf>(a); b = dpp_add_step<0x118,0xf>(b);
  c = dpp_add_step<0x118,0xf>(c); d = dpp_add_step<0x118,0xf>(d);
  a = dpp_add_step<0x142,0xa>(a); b = dpp_add_step<0x142,0xa>(b);
  c = dpp_add_step<0x142,0xa>(c); d = dpp_add_step<0x142,0xa>(d);
  a = dpp_add_step<0x143,0xc>(a); b = dpp_add_step<0x143,0xc>(b);
  c = dpp_add_step<0x143,0xc>(c); d = dpp_add_step<0x143,0xc>(d);
  ra = bcf(__builtin_amdgcn_readlane(bci(a), 63));
  rb = bcf(__builtin_amdgcn_readlane(bci(b), 63));
  rc = bcf(__builtin_amdgcn_readlane(bci(c), 63));
  rd = bcf(__builtin_amdgcn_readlane(bci(d), 63));
}
__device__ __forceinline__ float group16_sum(float x){
  x = dpp_add_step<0x111,0xf>(x);
  x = dpp_add_step<0x112,0xf>(x);
  x = dpp_add_step<0x114,0xf>(x);
  x = dpp_add_step<0x118,0xf>(x);
  return x;                          // lane 15 of each 16-group has group sum
}
template<int CTRL, int RM>
__device__ __forceinline__ float dpp_max_step(float x){
  int t = __builtin_amdgcn_update_dpp(bci(-3.4e38f), bci(x), CTRL, RM, 0xf, false);
  return fmaxf(x, bcf(t));
}
__device__ __forceinline__ float wave_max64(float x){
  x = dpp_max_step<0x111,0xf>(x);
  x = dpp_max_step<0x112,0xf>(x);
  x = dpp_max_step<0x114,0xf>(x);
  x = dpp_max_step<0x118,0xf>(x);
  x = dpp_max_step<0x142,0xa>(x);
  x = dpp_max_step<0x143,0xc>(x);
  return bcf(__builtin_amdgcn_readlane(bci(x), 63));
}

// =============== K0: prep, 256 blocks x 64 (1 quad/wave) ===============
// Quad p = blockIdx covers steps i = 4p+1 .. 4p+4 (p = 0..254). Slots:
//   s0 = {V1,V2,V3,V4}     dot vectors V_k = e_k * prod_{m<k} c_m
//   s1 = {Cq,T1,T2,T3}     z4 = Cq z0 + T1 d1 + T2 d2 + T3 d3 + T4 d4
//   s2 = {T4,m21,m31,m32}  r = M d (lower-tri, lane-uniform m's)
//   s3 = {m41,m42,m43,0}
// with S1=c4c3c2 s1, S2=c4c3 s2, S3=c4 s3, S4=s4;
//   m31=k31+k32 k21; m41=k41+k42 k21+k43 m31; m42=k42+k43 k32;
//   T4=S4; T3=S3+S4 m43; T2=S2+S3 m32+S4 m42; T1=S1+S2 m21+S3 m31+S4 m41.
// Also zeros A1p + ticket, and computes cont chunk sums cs32[32][64].
__global__ __launch_bounds__(64) void prep_kernel(
    const float* __restrict__ stop_logps,
    const float* __restrict__ start_logps,
    float* __restrict__ quadQ,   // [256][4][64][4] (quad 255 = dummy)
    float* __restrict__ cs32,    // [32][64]
    float* __restrict__ A1p,     // 64*1024, zeroed here
    int*   __restrict__ ticket)
{
  const int bid  = (int)blockIdx.x;   // 0..255
  const int lane = (int)threadIdx.x;
  const float KAPPA = 0.60653065971263342f;    // e^-0.5
  const float2* stop2 = (const float2*)stop_logps;

  // zero A1p: 65536 floats / 16384 threads = 4 each
  int g = bid * 64 + lane;
  A1p[g] = 0.f; A1p[g + 16384] = 0.f; A1p[g + 32768] = 0.f; A1p[g + 49152] = 0.f;
  if (bid == 255 && lane == 0) *ticket = 0;

  if (bid < 255) {
    const int i1 = 4 * bid + 1;
    float2 q1 = stop2[(i1 + 0) * B_N + lane];
    float2 q2 = stop2[(i1 + 1) * B_N + lane];
    float2 q3 = stop2[(i1 + 2) * B_N + lane];
    float2 q4 = stop2[(i1 + 3) * B_N + lane];
    float t1 = start_logps[(i1 + 0) * B_N + lane];
    float t2 = start_logps[(i1 + 1) * B_N + lane];
    float t3 = start_logps[(i1 + 2) * B_N + lane];
    float t4 = start_logps[(i1 + 3) * B_N + lane];
    float e1 = __expf(q1.x), c1 = __expf(q1.y), s1 = KAPPA * __expf(t1);
    float e2 = __expf(q2.x), c2 = __expf(q2.y), s2 = KAPPA * __expf(t2);
    float e3 = __expf(q3.x), c3 = __expf(q3.y), s3 = KAPPA * __expf(t3);
    float e4 = __expf(q4.x), c4 = __expf(q4.y), s4 = KAPPA * __expf(t4);

    float c21  = c2 * c1;
    float c321 = c3 * c21;
    float V1 = e1;
    float V2 = e2 * c1;
    float V3 = e3 * c21;
    float V4 = e4 * c321;

    float Cq = c4 * c321;
    float S1 = c4 * c3 * c2 * s1;
    float S2 = c4 * c3 * s2;
    float S3 = c4 * s3;
    float S4 = s4;

    float k21 = wave_sum64(e2 * s1);
    float k31 = wave_sum64(e3 * c2 * s1);
    float k32 = wave_sum64(e3 * s2);
    float k41 = wave_sum64(e4 * c3 * c2 * s1);
    float k42 = wave_sum64(e4 * c3 * s2);
    float k43 = wave_sum64(e4 * s3);

    float m21 = k21, m32 = k32, m43 = k43;
    float m31 = __builtin_fmaf(k32, k21, k31);
    float m42 = __builtin_fmaf(k43, k32, k42);
    float m41 = __builtin_fmaf(k43, m31, __builtin_fmaf(k42, k21, k41));

    float T4 = S4;
    float T3 = __builtin_fmaf(S4, m43, S3);
    float T2 = __builtin_fmaf(S4, m42, __builtin_fmaf(S3, m32, S2));
    float T1 = __builtin_fmaf(S4, m41,
               __builtin_fmaf(S3, m31, __builtin_fmaf(S2, m21, S1)));

    f32x4* qs = (f32x4*)quadQ;
    size_t base = (size_t)bid * 4 * 64 + lane;
    qs[base + 0 * 64] = (f32x4){V1, V2, V3, V4};
    qs[base + 1 * 64] = (f32x4){Cq, T1, T2, T3};
    qs[base + 2 * 64] = (f32x4){T4, m21, m31, m32};
    qs[base + 3 * 64] = (f32x4){m41, m42, m43, 0.f};
  }

  // cont chunk sums at 32-granularity (chunk c = i in [32c+1, 32c+32])
  if (bid < 32) {
    float s = 0.f;
    for (int k = 1; k <= 32; ++k) {
      int i = 32 * bid + k;
      if (i <= 1023) s += stop2[i * B_N + lane].y;
    }
    cs32[bid * B_N + lane] = s;
  }
}

// =============== K1: serial scan, quad steps, d-direct z4 jump ===============
// Critical chain per quad: mul -> 6 DPP -> readlane -> depth-3 fma tree.
// r-solve (r = M d) is off the critical path (only feeds stores).
// Boundary z rows stored POST-rescale at 32-multiples (rows 32..992);
// window-of-16 rescale at p%4==3, exponent of r4. r_ws[i-1] = r at step i.
__global__ __launch_bounds__(64, 1) void scan_kernel(
    const float* __restrict__ stop_logps,
    const float* __restrict__ start_logps,
    const float* __restrict__ quadQ,
    float* __restrict__ z_ws,     // rows 32w (w=1..31) only, post-rescale
    float* __restrict__ r_ws,     // 1024; r_ws[i-1] = r at step i
    float* __restrict__ wexp)     // 64 (0..62 used)
{
  const int lane = threadIdx.x;
  const float2* stop2 = (const float2*)stop_logps;

  // prefetch tail-single coefficients (steps 1021..1023) now
  float2 sct0 = stop2[1021 * B_N + lane];
  float2 sct1 = stop2[1022 * B_N + lane];
  float2 sct2 = stop2[1023 * B_N + lane];
  float stt0 = start_logps[1021 * B_N + lane];
  float stt1 = start_logps[1022 * B_N + lane];
  float stt2 = start_logps[1023 * B_N + lane];

  float z = __expf(start_logps[lane]);   // y_0, scale P=0

  const f32x4* qs = (const f32x4*)quadQ;

  // 8-quad (32-step) rotating prefetch
  f32x4 qb[8][4];
  #pragma unroll
  for (int q = 0; q < 8; ++q)
    #pragma unroll
    for (int s = 0; s < 4; ++s)
      qb[q][s] = qs[((size_t)q * 4 + s) * 64 + lane];

  for (int p0 = 0; p0 < 248; p0 += 8) {
    #pragma unroll
    for (int q = 0; q < 8; ++q) {
      const int p = p0 + q;
      f32x4 V = qb[q][0];
      f32x4 Z = qb[q][1];   // {Cq,T1,T2,T3}
      f32x4 W = qb[q][2];   // {T4,m21,m31,m32}
      f32x4 X = qb[q][3];   // {m41,m42,m43,-}
      // prefetch quad p+8 (quad 255 is a dummy slot, loaded but never used)
      {
        const int pn = p + 8;
        #pragma unroll
        for (int s = 0; s < 4; ++s)
          qb[q][s] = qs[((size_t)pn * 4 + s) * 64 + lane];
      }

      float d1, d2, d3, d4;
      wave_sum64_x4(z * V.x, z * V.y, z * V.z, z * V.w, d1, d2, d3, d4);

      // r-solve (off critical path; values are lane-uniform)
      float r1 = d1;
      float r2 = __builtin_fmaf(W.y, d1, d2);
      float r3 = __builtin_fmaf(W.w, d2, __builtin_fmaf(W.z, d1, d3));
      float r4 = __builtin_fmaf(X.z, d3,
                 __builtin_fmaf(X.y, d2, __builtin_fmaf(X.x, d1, d4)));
      if (lane == 0) *(f32x4*)(r_ws + 4 * p) = (f32x4){r1, r2, r3, r4};

      // z4 jump directly from d's (depth-3 tree)
      float p1 = __builtin_fmaf(d2, Z.z, __builtin_fmaf(d1, Z.y, z * Z.x));
      float p2 = __builtin_fmaf(d4, W.x, d3 * Z.w);
      z = p1 + p2;

      if ((q & 3) == 3) {                 // step 16m+16: window boundary
        int rb  = bci(r4);
        int e16 = ((rb >> 23) & 255) - 127;
        z = ldexpf(z, -e16);
        if (lane == 0) wexp[p >> 2] = (float)e16;
        if (q == 7)                       // row 4p+4 = 32-multiple
          z_ws[(4 * p + 4) * B_N + lane] = z;   // post-rescale boundary row
      }
    }
  }
  // tail quads 248..254 (steps 993..1020); rescale only at p==251 (step 1008)
  #pragma unroll
  for (int q = 0; q < 7; ++q) {
    const int p = 248 + q;
    f32x4 V = qb[q][0];
    f32x4 Z = qb[q][1];
    f32x4 W = qb[q][2];
    f32x4 X = qb[q][3];
    float d1, d2, d3, d4;
    wave_sum64_x4(z * V.x, z * V.y, z * V.z, z * V.w, d1, d2, d3, d4);
    float r1 = d1;
    float r2 = __builtin_fmaf(W.y, d1, d2);
    float r3 = __builtin_fmaf(W.w, d2, __builtin_fmaf(W.z, d1, d3));
    float r4 = __builtin_fmaf(X.z, d3,
               __builtin_fmaf(X.y, d2, __builtin_fmaf(X.x, d1, d4)));
    if (lane == 0) *(f32x4*)(r_ws + 4 * p) = (f32x4){r1, r2, r3, r4};
    float p1 = __builtin_fmaf(d2, Z.z, __builtin_fmaf(d1, Z.y, z * Z.x));
    float p2 = __builtin_fmaf(d4, W.x, d3 * Z.w);
    z = p1 + p2;
    if (q == 3) {                         // p==251, step 1008 boundary
      int rb  = bci(r4);
      int e16 = ((rb >> 23) & 255) - 127;
      z = ldexpf(z, -e16);
      if (lane == 0) wexp[62] = (float)e16;
    }
  }
  // singles: steps 1021..1023 (window 63, no rescale; r only)
  const float KAPPA = 0.60653065971263342f;
  {
    float esw = __expf(sct0.x), ecw = __expf(sct0.y), sv = KAPPA * __expf(stt0);
    float r = wave_sum64(z * esw);
    z = __builtin_fmaf(sv, r, z * ecw);
    if (lane == 0) r_ws[1020] = r;
  }
  {
    float esw = __expf(sct1.x), ecw = __expf(sct1.y), sv = KAPPA * __expf(stt1);
    float r = wave_sum64(z * esw);
    z = __builtin_fmaf(sv, r, z * ecw);
    if (lane == 0) r_ws[1021] = r;
  }
  {
    float esw = __expf(sct2.x), ecw = __expf(sct2.y), sv = KAPPA * __expf(stt2);
    float r = wave_sum64(z * esw);
    z = __builtin_fmaf(sv, r, z * ecw);
    if (lane == 0) r_ws[1022] = r;
  }
}

// =============== K2: bookkeeping, 32 parallel blocks (1 wave each) ===============
// Block w handles i in [32w+1, min(32w+32,1023)]. Entry z = z_ws[32w]
// (already in window-2w scale). One in-chunk rescale at k==16 (window 2w).
__global__ __launch_bounds__(64) void post_kernel(
    const int* __restrict__ actions,
    const float* __restrict__ action_logps,
    const float* __restrict__ stop_logps,
    const float* __restrict__ start_logps,
    const float* __restrict__ z_ws,
    const float* __restrict__ r_ws,
    const float* __restrict__ wexp,
    const float* __restrict__ cs32,
    float* __restrict__ u_ws,
    float* __restrict__ D_ws,
    float* __restrict__ out)
{
  const int w    = (int)blockIdx.x;   // 0..31
  const int lane = (int)threadIdx.x;  // = b
  const float LN2   = 0.69314718055994531f;
  const float KAPPA = 0.60653065971263342f;
  const float2* stop2 = (const float2*)stop_logps;

  float wl = (lane < 63) ? wexp[lane] : 0.f;

  // window-scale prefix entering window 2w
  float Pv = LN2 * wave_sum64((lane < 2 * w) ? wl : 0.f);
  // boundary exponent for window 2w (applied after k=16)
  float e0 = bcf(__builtin_amdgcn_readlane(bci(wl), 2 * w));

  // cont-logp prefix entering the chunk
  float C = 0.f;
  for (int c = 0; c < w; ++c) C += cs32[c * B_N + lane];

  // chunk-entry z (window-2w scale)
  float z;
  if (w == 0) {
    z = __expf(start_logps[lane]);
    u_ws[lane] = start_logps[lane];       // u_0 = st0
  } else {
    z = z_ws[(32 * w) * B_N + lane];      // stored post-rescale by the scan
  }

  for (int k = 1; k <= 32; ++k) {
    int i = 32 * w + k;
    if (i > 1023) break;
    float cont = stop2[i * B_N + lane].y;
    float stv  = start_logps[i * B_N + lane];
    float r    = r_ws[i - 1];
    C += cont;
    float ecw = __expf(cont);
    float sv  = KAPPA * __expf(stv);
    z = __builtin_fmaf(r, sv, ecw * z);
    float zs = wave_sum64(z);
    float R  = __logf(r) + Pv - 0.5f;
    u_ws[i * B_N + lane] = stv + R - C;
    D_ws[i * B_N + lane] = C - (__logf(zs) + Pv);
    if (k == 16) { z = ldexpf(z, -(int)e0); Pv += LN2 * e0; }
  }

  if (w == 31) {                          // z = z_1023 (window-63 scale), Pv = P(63)
    float st0 = start_logps[lane];
    int   a0  = actions[0];
    float al0 = action_logps[lane * A_N + a0];
    float lp0 = __logf(wave_sum64(__expf(st0 + al0)));
    float stopT = stop_logps[(T_N * B_N + lane) * 2 + 0];
    float fin = __logf(wave_sum64(z * __expf(stopT))) + Pv;
    if (lane == 0) out[0] = -(lp0 + fin);
  }
}

// =============== K34: fused consistency + logp + last-block finish ===============
// blocks 0..511   : cons rows j = bid and 1023-bid (constant 1025 rows/block)
// blocks 512..1534: logp term for i = 1535-bid (1023..1, longest first)
// Last block (ticket) performs the finish reduction with agent-scope atomic
// loads (per-XCD L2s are not coherent; A1p was written via device atomics,
// LQ via tid0 plain store + tid0 release fence before the ticket add).
__global__ __launch_bounds__(256) void cons_logp_kernel(
    const float* __restrict__ cons_pen,
    const float* __restrict__ u_ws,
    const float* __restrict__ D_ws,
    const int* __restrict__ actions,
    const float* __restrict__ action_logps,
    float* __restrict__ A1p,
    float* __restrict__ LQ,
    int*   __restrict__ ticket,
    float* __restrict__ out)
{
  const int bid  = (int)blockIdx.x;
  const int tid  = (int)threadIdx.x;
  const int lane = tid & 63;
  const int wv   = tid >> 6;

  __shared__ float sm[4][64];
  __shared__ float sa[4][64];
  __shared__ float sb[4];
  __shared__ int sdone;

  if (bid < 512) {
    const int bq  = (lane & 15) * 4;
    const int row = lane >> 4;
    #pragma unroll
    for (int t = 0; t < 2; ++t) {
      const int j = t ? (1023 - bid) : bid;
      const float4 u4 = *(const float4*)(u_ws + j * B_N + bq);
      float* dst = A1p + ((j & 63) << 10);
      for (int i0 = j + 4 * wv; i0 <= 1023; i0 += 16) {
        int i  = i0 + row;
        int iL = i > 1023 ? 1023 : i;
        f32x4 cp4 = __builtin_nontemporal_load(
            (const f32x4*)(cons_pen + ((size_t)j * TP1 + iL) * B_N + bq));
        float4 d4  = *(const float4*)(D_ws + (size_t)iL * B_N + bq);
        bool valid = (i >= 1) && (i <= 1023);
        float a0 = u4.x + d4.x + cp4.x;
        float a1 = u4.y + d4.y + cp4.y;
        float a2 = u4.z + d4.z + cp4.z;
        float a3 = u4.w + d4.w + cp4.w;
        a0 = valid ? a0 : -1e30f;
        a1 = valid ? a1 : -1e30f;
        a2 = valid ? a2 : -1e30f;
        a3 = valid ? a3 : -1e30f;
        float sred = (__expf(a0) + __expf(a1)) + (__expf(a2) + __expf(a3));
        sred = group16_sum(sred);
        if (((lane & 15) == 15) && valid) atomicAdd(dst + i, sred);
      }
    }
  } else {
    const int i = 1535 - bid;   // 1023..1
    int   ai = actions[i];
    float av = action_logps[((size_t)i * B_N + lane) * A_N + ai];

    // two independent online-softmax chains (halved dependent latency)
    float mA = -1e30f, aA = 0.f, mB = -1e30f, aB = 0.f;
    for (int jj = wv; jj <= i; jj += 8) {
      float u0 = u_ws[jj * B_N + lane];
      int   j1 = jj + 4;
      float u1 = (j1 <= i) ? u_ws[j1 * B_N + lane] : -1e30f;
      float n0 = fmaxf(mA, u0);
      aA = aA * __expf(mA - n0) + __expf(u0 - n0);
      mA = n0;
      float n1 = fmaxf(mB, u1);
      aB = aB * __expf(mB - n1) + __expf(u1 - n1);
      mB = n1;
    }
    float m   = fmaxf(mA, mB);
    float acc = aA * __expf(mA - m) + aB * __expf(mB - m);

    sm[wv][lane] = m; sa[wv][lane] = acc;
    __syncthreads();
    if (wv == 0) {
      float m0 = sm[0][lane], m1 = sm[1][lane], m2 = sm[2][lane], m3 = sm[3][lane];
      float M2 = fmaxf(fmaxf(m0, m1), fmaxf(m2, m3));
      float A  = sa[0][lane] * __expf(m0 - M2) + sa[1][lane] * __expf(m1 - M2)
               + sa[2][lane] * __expf(m2 - M2) + sa[3][lane] * __expf(m3 - M2);
      float S  = M2 + __logf(A);
      float val = S + D_ws[(size_t)i * B_N + lane] + av;
      float mx  = wave_max64(val);
      float sum = wave_sum64(__expf(val - mx));
      if (lane == 0) LQ[i] = mx + __logf(sum);
    }
  }

  // ---- last-block finish ----
  __syncthreads();
  if (tid == 0) {
    __threadfence();                       // release: LQ store (tid0) + atomics
    int old = atomicAdd(ticket, 1);
    sdone = (old == 1534) ? 1 : 0;
  }
  __syncthreads();
  if (sdone) {
    __threadfence();                       // acquire side
    float vsum = 0.f;
    for (int rep = 0; rep < 4; ++rep) {
      int i = rep * 256 + tid;
      if (i >= 1 && i <= 1023) {
        float a = 0.f;
        #pragma unroll 8
        for (int pq = 0; pq < 64; ++pq)
          a += __hip_atomic_load(&A1p[(pq << 10) + i],
                                 __ATOMIC_RELAXED, __HIP_MEMORY_SCOPE_AGENT);
        float lq = __hip_atomic_load(&LQ[i],
                                 __ATOMIC_RELAXED, __HIP_MEMORY_SCOPE_AGENT);
        vsum += __logf(a) - lq;
      }
    }
    float ws = wave_sum64(vsum);
    if (lane == 0) sb[wv] = ws;
    __syncthreads();
    if (tid == 0) atomicAdd(out, sb[0] + sb[1] + sb[2] + sb[3]);
  }
}

extern "C" void kernel_launch(void* const* d_in, const int* in_sizes, int n_in,
                              void* d_out, int out_size, void* d_ws, size_t ws_size,
                              hipStream_t stream) {
  const int*   actions      = (const int*)d_in[0];
  const float* action_logps = (const float*)d_in[1];
  const float* stop_logps   = (const float*)d_in[2];
  const float* start_logps  = (const float*)d_in[3];
  const float* cons_pen     = (const float*)d_in[4];
  float* out = (float*)d_out;

  float* z_ws  = (float*)d_ws;                  // 1024*64 (only rows 32w used)
  float* u_ws  = z_ws + T_N * B_N;              // 1024*64
  float* D_ws  = u_ws + T_N * B_N;              // 1024*64
  float* A1p   = D_ws + T_N * B_N;              // 64*1024
  float* r_ws  = A1p + 64 * 1024;               // 1024 (16B aligned)
  float* wexp  = r_ws + T_N;                    // 64
  float* LQ    = wexp + 64;                     // 1024
  float* cs32  = LQ + T_N;                      // 32*64
  float* quadQ = cs32 + 32 * B_N;               // 256*4*64*4 floats (16B aligned)
  int*   ticket = (int*)(quadQ + 256 * 4 * B_N * 4); // 1 int, PAST end of quadQ

  hipLaunchKernelGGL(prep_kernel, dim3(256), dim3(64), 0, stream,
                     stop_logps, start_logps, quadQ, cs32, A1p, ticket);
  hipLaunchKernelGGL(scan_kernel, dim3(1), dim3(64), 0, stream,
                     stop_logps, start_logps, quadQ, z_ws, r_ws, wexp);
  hipLaunchKernelGGL(post_kernel, dim3(32), dim3(64), 0, stream,
                     actions, action_logps, stop_logps, start_logps,
                     z_ws, r_ws, wexp, cs32, u_ws, D_ws, out);
  hipLaunchKernelGGL(cons_logp_kernel, dim3(1535), dim3(256), 0, stream,
                     cons_pen, u_ws, D_ws, actions, action_logps, A1p, LQ,
                     ticket, out);
}

// Round 6
// 463.236 us; speedup vs baseline: 1.0945x; 1.0945x over previous
//
#include <hip/hip_runtime.h>

#define T_N 1024
#define B_N 64
#define A_N 128
#define TP1 1025
// STOP_IX=0, CONT_IX=1, ABSTRACT_PENALTY=0.5, CONSISTENCY_RATIO=1.0

typedef float f32x4 __attribute__((ext_vector_type(4)));

__device__ __forceinline__ float bcf(int x){ return __builtin_bit_cast(float, x); }
__device__ __forceinline__ int   bci(float x){ return __builtin_bit_cast(int, x); }

// ---- DPP helpers ----
template<int CTRL, int RM>
__device__ __forceinline__ float dpp_add_step(float x){
  int t = __builtin_amdgcn_update_dpp(0, bci(x), CTRL, RM, 0xf, true);
  return x + bcf(t);
}
__device__ __forceinline__ float wave_sum64(float x){
  x = dpp_add_step<0x111,0xf>(x);   // row_shr:1
  x = dpp_add_step<0x112,0xf>(x);   // row_shr:2
  x = dpp_add_step<0x114,0xf>(x);   // row_shr:4
  x = dpp_add_step<0x118,0xf>(x);   // row_shr:8
  x = dpp_add_step<0x142,0xa>(x);   // row_bcast15
  x = dpp_add_step<0x143,0xc>(x);   // row_bcast31; lane63 = total
  return bcf(__builtin_amdgcn_readlane(bci(x), 63));
}
// four interleaved reductions: ~1 chain latency for 4 sums
__device__ __forceinline__ void wave_sum64_x4(float a, float b, float c, float d,
                                              float& ra, float& rb, float& rc, float& rd){
  a = dpp_add_step<0x111,0xf>(a); b = dpp_add_step<0x111,0xf>(b);
  c = dpp_add_step<0x111,0xf>(c); d = dpp_add_step<0x111,0xf>(d);
  a = dpp_add_step<0x112,0xf>(a); b = dpp_add_step<0x112,0xf>(b);
  c = dpp_add_step<0x112,0xf>(c); d = dpp_add_step<0x112,0xf>(d);
  a = dpp_add_step<0x114,0xf>(a); b = dpp_add_step<0x114,0xf>(b);
  c = dpp_add_step<0x114,0xf>(c); d = dpp_add_step<0x114,0xf>(d);
  a = dpp_add_step<0x118,0xf>(a); b = dpp_add_step<0x118,0xf>(b);
  c = dpp_add_step<0x118,0xf>(c); d = dpp_add_step<0x118,0xf>(d);
  a = dpp_add_step<0x142,0xa>(a); b = dpp_add_step<0x142,0xa>(b);
  c = dpp_add_step<0x142,0xa>(c); d = dpp_add_step<0x142,0xa>(d);
  a = dpp_add_step<0x143,0xc>(a); b = dpp_add_step<0x143,0xc>(b);
  c = dpp_add_step<0x143,0xc>(c); d = dpp_add_step<0x143,0xc>(d);
  ra = bcf(__builtin_amdgcn_readlane(bci(a), 63));
  rb = bcf(__builtin_amdgcn_readlane(bci(b), 63));
  rc = bcf(__builtin_amdgcn_readlane(bci(c), 63));
  rd = bcf(__builtin_amdgcn_readlane(bci(d), 63));
}
__device__ __forceinline__ float group16_sum(float x){
  x = dpp_add_step<0x111,0xf>(x);
  x = dpp_add_step<0x112,0xf>(x);
  x = dpp_add_step<0x114,0xf>(x);
  x = dpp_add_step<0x118,0xf>(x);
  return x;                          // lane 15 of each 16-group has group sum
}
template<int CTRL, int RM>
__device__ __forceinline__ float dpp_max_step(float x){
  int t = __builtin_amdgcn_update_dpp(bci(-3.4e38f), bci(x), CTRL, RM, 0xf, false);
  return fmaxf(x, bcf(t));
}
__device__ __forceinline__ float wave_max64(float x){
  x = dpp_max_step<0x111,0xf>(x);
  x = dpp_max_step<0x112,0xf>(x);
  x = dpp_max_step<0x114,0xf>(x);
  x = dpp_max_step<0x118,0xf>(x);
  x = dpp_max_step<0x142,0xa>(x);
  x = dpp_max_step<0x143,0xc>(x);
  return bcf(__builtin_amdgcn_readlane(bci(x), 63));
}

// =============== K0: prep, 256 blocks x 64 (1 quad/wave) ===============
// Quad p = blockIdx covers steps i = 4p+1 .. 4p+4 (p = 0..254). Slots:
//   s0 = {V1,V2,V3,V4}     dot vectors V_k = e_k * prod_{m<k} c_m
//   s1 = {Cq,T1,T2,T3}     z4 = Cq z0 + T1 d1 + T2 d2 + T3 d3 + T4 d4
//   s2 = {T4,m21,m31,m32}  r = M d (lower-tri, lane-uniform m's)
//   s3 = {m41,m42,m43,0}
// with S1=c4c3c2 s1, S2=c4c3 s2, S3=c4 s3, S4=s4;
//   m31=k31+k32 k21; m41=k41+k42 k21+k43 m31; m42=k42+k43 k32;
//   T4=S4; T3=S3+S4 m43; T2=S2+S3 m32+S4 m42; T1=S1+S2 m21+S3 m31+S4 m41.
// Also zeros A1p and computes cont chunk sums cs32[32][64].
__global__ __launch_bounds__(64) void prep_kernel(
    const float* __restrict__ stop_logps,
    const float* __restrict__ start_logps,
    float* __restrict__ quadQ,   // [256][4][64][4] (quad 255 = dummy)
    float* __restrict__ cs32,    // [32][64]
    float* __restrict__ A1p)     // 64*1024, zeroed here
{
  const int bid  = (int)blockIdx.x;   // 0..255
  const int lane = (int)threadIdx.x;
  const float KAPPA = 0.60653065971263342f;    // e^-0.5
  const float2* stop2 = (const float2*)stop_logps;

  // zero A1p: 65536 floats / 16384 threads = 4 each
  int g = bid * 64 + lane;
  A1p[g] = 0.f; A1p[g + 16384] = 0.f; A1p[g + 32768] = 0.f; A1p[g + 49152] = 0.f;

  if (bid < 255) {
    const int i1 = 4 * bid + 1;
    float2 q1 = stop2[(i1 + 0) * B_N + lane];
    float2 q2 = stop2[(i1 + 1) * B_N + lane];
    float2 q3 = stop2[(i1 + 2) * B_N + lane];
    float2 q4 = stop2[(i1 + 3) * B_N + lane];
    float t1 = start_logps[(i1 + 0) * B_N + lane];
    float t2 = start_logps[(i1 + 1) * B_N + lane];
    float t3 = start_logps[(i1 + 2) * B_N + lane];
    float t4 = start_logps[(i1 + 3) * B_N + lane];
    float e1 = __expf(q1.x), c1 = __expf(q1.y), s1 = KAPPA * __expf(t1);
    float e2 = __expf(q2.x), c2 = __expf(q2.y), s2 = KAPPA * __expf(t2);
    float e3 = __expf(q3.x), c3 = __expf(q3.y), s3 = KAPPA * __expf(t3);
    float e4 = __expf(q4.x), c4 = __expf(q4.y), s4 = KAPPA * __expf(t4);

    float c21  = c2 * c1;
    float c321 = c3 * c21;
    float V1 = e1;
    float V2 = e2 * c1;
    float V3 = e3 * c21;
    float V4 = e4 * c321;

    float Cq = c4 * c321;
    float S1 = c4 * c3 * c2 * s1;
    float S2 = c4 * c3 * s2;
    float S3 = c4 * s3;
    float S4 = s4;

    float k21 = wave_sum64(e2 * s1);
    float k31 = wave_sum64(e3 * c2 * s1);
    float k32 = wave_sum64(e3 * s2);
    float k41 = wave_sum64(e4 * c3 * c2 * s1);
    float k42 = wave_sum64(e4 * c3 * s2);
    float k43 = wave_sum64(e4 * s3);

    float m21 = k21, m32 = k32, m43 = k43;
    float m31 = __builtin_fmaf(k32, k21, k31);
    float m42 = __builtin_fmaf(k43, k32, k42);
    float m41 = __builtin_fmaf(k43, m31, __builtin_fmaf(k42, k21, k41));

    float T4 = S4;
    float T3 = __builtin_fmaf(S4, m43, S3);
    float T2 = __builtin_fmaf(S4, m42, __builtin_fmaf(S3, m32, S2));
    float T1 = __builtin_fmaf(S4, m41,
               __builtin_fmaf(S3, m31, __builtin_fmaf(S2, m21, S1)));

    f32x4* qs = (f32x4*)quadQ;
    size_t base = (size_t)bid * 4 * 64 + lane;
    qs[base + 0 * 64] = (f32x4){V1, V2, V3, V4};
    qs[base + 1 * 64] = (f32x4){Cq, T1, T2, T3};
    qs[base + 2 * 64] = (f32x4){T4, m21, m31, m32};
    qs[base + 3 * 64] = (f32x4){m41, m42, m43, 0.f};
  }

  // cont chunk sums at 32-granularity (chunk c = i in [32c+1, 32c+32])
  if (bid < 32) {
    float s = 0.f;
    for (int k = 1; k <= 32; ++k) {
      int i = 32 * bid + k;
      if (i <= 1023) s += stop2[i * B_N + lane].y;
    }
    cs32[bid * B_N + lane] = s;
  }
}

// =============== K1: serial scan, quad steps, d-direct z4 jump ===============
// Critical chain per quad: mul -> 6 DPP -> readlane -> depth-3 fma tree.
// r-solve (r = M d) is off the critical path (only feeds stores).
// Boundary z rows stored POST-rescale at 32-multiples (rows 32..992);
// window-of-16 rescale at p%4==3, exponent of r4. r_ws[i-1] = r at step i.
__global__ __launch_bounds__(64, 1) void scan_kernel(
    const float* __restrict__ stop_logps,
    const float* __restrict__ start_logps,
    const float* __restrict__ quadQ,
    float* __restrict__ z_ws,     // rows 32w (w=1..31) only, post-rescale
    float* __restrict__ r_ws,     // 1024; r_ws[i-1] = r at step i
    float* __restrict__ wexp)     // 64 (0..62 used)
{
  const int lane = threadIdx.x;
  const float2* stop2 = (const float2*)stop_logps;

  // prefetch tail-single coefficients (steps 1021..1023) now
  float2 sct0 = stop2[1021 * B_N + lane];
  float2 sct1 = stop2[1022 * B_N + lane];
  float2 sct2 = stop2[1023 * B_N + lane];
  float stt0 = start_logps[1021 * B_N + lane];
  float stt1 = start_logps[1022 * B_N + lane];
  float stt2 = start_logps[1023 * B_N + lane];

  float z = __expf(start_logps[lane]);   // y_0, scale P=0

  const f32x4* qs = (const f32x4*)quadQ;

  // 8-quad (32-step) rotating prefetch
  f32x4 qb[8][4];
  #pragma unroll
  for (int q = 0; q < 8; ++q)
    #pragma unroll
    for (int s = 0; s < 4; ++s)
      qb[q][s] = qs[((size_t)q * 4 + s) * 64 + lane];

  for (int p0 = 0; p0 < 248; p0 += 8) {
    #pragma unroll
    for (int q = 0; q < 8; ++q) {
      const int p = p0 + q;
      f32x4 V = qb[q][0];
      f32x4 Z = qb[q][1];   // {Cq,T1,T2,T3}
      f32x4 W = qb[q][2];   // {T4,m21,m31,m32}
      f32x4 X = qb[q][3];   // {m41,m42,m43,-}
      // prefetch quad p+8 (quad 255 is a dummy slot, loaded but never used)
      {
        const int pn = p + 8;
        #pragma unroll
        for (int s = 0; s < 4; ++s)
          qb[q][s] = qs[((size_t)pn * 4 + s) * 64 + lane];
      }

      float d1, d2, d3, d4;
      wave_sum64_x4(z * V.x, z * V.y, z * V.z, z * V.w, d1, d2, d3, d4);

      // r-solve (off critical path; values are lane-uniform)
      float r1 = d1;
      float r2 = __builtin_fmaf(W.y, d1, d2);
      float r3 = __builtin_fmaf(W.w, d2, __builtin_fmaf(W.z, d1, d3));
      float r4 = __builtin_fmaf(X.z, d3,
                 __builtin_fmaf(X.y, d2, __builtin_fmaf(X.x, d1, d4)));
      if (lane == 0) *(f32x4*)(r_ws + 4 * p) = (f32x4){r1, r2, r3, r4};

      // z4 jump directly from d's (depth-3 tree)
      float p1 = __builtin_fmaf(d2, Z.z, __builtin_fmaf(d1, Z.y, z * Z.x));
      float p2 = __builtin_fmaf(d4, W.x, d3 * Z.w);
      z = p1 + p2;

      if ((q & 3) == 3) {                 // step 16m+16: window boundary
        int rb  = bci(r4);
        int e16 = ((rb >> 23) & 255) - 127;
        z = ldexpf(z, -e16);
        if (lane == 0) wexp[p >> 2] = (float)e16;
        if (q == 7)                       // row 4p+4 = 32-multiple
          z_ws[(4 * p + 4) * B_N + lane] = z;   // post-rescale boundary row
      }
    }
  }
  // tail quads 248..254 (steps 993..1020); rescale only at p==251 (step 1008)
  #pragma unroll
  for (int q = 0; q < 7; ++q) {
    const int p = 248 + q;
    f32x4 V = qb[q][0];
    f32x4 Z = qb[q][1];
    f32x4 W = qb[q][2];
    f32x4 X = qb[q][3];
    float d1, d2, d3, d4;
    wave_sum64_x4(z * V.x, z * V.y, z * V.z, z * V.w, d1, d2, d3, d4);
    float r1 = d1;
    float r2 = __builtin_fmaf(W.y, d1, d2);
    float r3 = __builtin_fmaf(W.w, d2, __builtin_fmaf(W.z, d1, d3));
    float r4 = __builtin_fmaf(X.z, d3,
               __builtin_fmaf(X.y, d2, __builtin_fmaf(X.x, d1, d4)));
    if (lane == 0) *(f32x4*)(r_ws + 4 * p) = (f32x4){r1, r2, r3, r4};
    float p1 = __builtin_fmaf(d2, Z.z, __builtin_fmaf(d1, Z.y, z * Z.x));
    float p2 = __builtin_fmaf(d4, W.x, d3 * Z.w);
    z = p1 + p2;
    if (q == 3) {                         // p==251, step 1008 boundary
      int rb  = bci(r4);
      int e16 = ((rb >> 23) & 255) - 127;
      z = ldexpf(z, -e16);
      if (lane == 0) wexp[62] = (float)e16;
    }
  }
  // singles: steps 1021..1023 (window 63, no rescale; r only)
  const float KAPPA = 0.60653065971263342f;
  {
    float esw = __expf(sct0.x), ecw = __expf(sct0.y), sv = KAPPA * __expf(stt0);
    float r = wave_sum64(z * esw);
    z = __builtin_fmaf(sv, r, z * ecw);
    if (lane == 0) r_ws[1020] = r;
  }
  {
    float esw = __expf(sct1.x), ecw = __expf(sct1.y), sv = KAPPA * __expf(stt1);
    float r = wave_sum64(z * esw);
    z = __builtin_fmaf(sv, r, z * ecw);
    if (lane == 0) r_ws[1021] = r;
  }
  {
    float esw = __expf(sct2.x), ecw = __expf(sct2.y), sv = KAPPA * __expf(stt2);
    float r = wave_sum64(z * esw);
    z = __builtin_fmaf(sv, r, z * ecw);
    if (lane == 0) r_ws[1022] = r;
  }
}

// =============== K2: bookkeeping, 32 parallel blocks (1 wave each) ===============
// Block w handles i in [32w+1, min(32w+32,1023)]. Entry z = z_ws[32w]
// (already in window-2w scale). One in-chunk rescale at k==16 (window 2w).
__global__ __launch_bounds__(64) void post_kernel(
    const int* __restrict__ actions,
    const float* __restrict__ action_logps,
    const float* __restrict__ stop_logps,
    const float* __restrict__ start_logps,
    const float* __restrict__ z_ws,
    const float* __restrict__ r_ws,
    const float* __restrict__ wexp,
    const float* __restrict__ cs32,
    float* __restrict__ u_ws,
    float* __restrict__ D_ws,
    float* __restrict__ out)
{
  const int w    = (int)blockIdx.x;   // 0..31
  const int lane = (int)threadIdx.x;  // = b
  const float LN2   = 0.69314718055994531f;
  const float KAPPA = 0.60653065971263342f;
  const float2* stop2 = (const float2*)stop_logps;

  float wl = (lane < 63) ? wexp[lane] : 0.f;

  // window-scale prefix entering window 2w
  float Pv = LN2 * wave_sum64((lane < 2 * w) ? wl : 0.f);
  // boundary exponent for window 2w (applied after k=16)
  float e0 = bcf(__builtin_amdgcn_readlane(bci(wl), 2 * w));

  // cont-logp prefix entering the chunk
  float C = 0.f;
  for (int c = 0; c < w; ++c) C += cs32[c * B_N + lane];

  // chunk-entry z (window-2w scale)
  float z;
  if (w == 0) {
    z = __expf(start_logps[lane]);
    u_ws[lane] = start_logps[lane];       // u_0 = st0
  } else {
    z = z_ws[(32 * w) * B_N + lane];      // stored post-rescale by the scan
  }

  for (int k = 1; k <= 32; ++k) {
    int i = 32 * w + k;
    if (i > 1023) break;
    float cont = stop2[i * B_N + lane].y;
    float stv  = start_logps[i * B_N + lane];
    float r    = r_ws[i - 1];
    C += cont;
    float ecw = __expf(cont);
    float sv  = KAPPA * __expf(stv);
    z = __builtin_fmaf(r, sv, ecw * z);
    float zs = wave_sum64(z);
    float R  = __logf(r) + Pv - 0.5f;
    u_ws[i * B_N + lane] = stv + R - C;
    D_ws[i * B_N + lane] = C - (__logf(zs) + Pv);
    if (k == 16) { z = ldexpf(z, -(int)e0); Pv += LN2 * e0; }
  }

  if (w == 31) {                          // z = z_1023 (window-63 scale), Pv = P(63)
    float st0 = start_logps[lane];
    int   a0  = actions[0];
    float al0 = action_logps[lane * A_N + a0];
    float lp0 = __logf(wave_sum64(__expf(st0 + al0)));
    float stopT = stop_logps[(T_N * B_N + lane) * 2 + 0];
    float fin = __logf(wave_sum64(z * __expf(stopT))) + Pv;
    if (lane == 0) out[0] = -(lp0 + fin);
  }
}

// =============== K34: fused consistency + logp ===============
// blocks 0..511   : cons rows j = bid and 1023-bid (constant 1025 rows/block)
// blocks 512..1534: logp term for i = 1535-bid (1023..1, longest first)
__global__ __launch_bounds__(256) void cons_logp_kernel(
    const float* __restrict__ cons_pen,
    const float* __restrict__ u_ws,
    const float* __restrict__ D_ws,
    const int* __restrict__ actions,
    const float* __restrict__ action_logps,
    float* __restrict__ A1p,
    float* __restrict__ LQ)
{
  const int bid  = (int)blockIdx.x;
  const int tid  = (int)threadIdx.x;
  const int lane = tid & 63;
  const int wv   = tid >> 6;

  __shared__ float sm[4][64];
  __shared__ float sa[4][64];

  if (bid < 512) {
    const int bq  = (lane & 15) * 4;
    const int row = lane >> 4;
    #pragma unroll
    for (int t = 0; t < 2; ++t) {
      const int j = t ? (1023 - bid) : bid;
      const float4 u4 = *(const float4*)(u_ws + j * B_N + bq);
      float* dst = A1p + ((j & 63) << 10);
      for (int i0 = j + 4 * wv; i0 <= 1023; i0 += 16) {
        int i  = i0 + row;
        int iL = i > 1023 ? 1023 : i;
        f32x4 cp4 = __builtin_nontemporal_load(
            (const f32x4*)(cons_pen + ((size_t)j * TP1 + iL) * B_N + bq));
        float4 d4  = *(const float4*)(D_ws + (size_t)iL * B_N + bq);
        bool valid = (i >= 1) && (i <= 1023);
        float a0 = u4.x + d4.x + cp4.x;
        float a1 = u4.y + d4.y + cp4.y;
        float a2 = u4.z + d4.z + cp4.z;
        float a3 = u4.w + d4.w + cp4.w;
        a0 = valid ? a0 : -1e30f;
        a1 = valid ? a1 : -1e30f;
        a2 = valid ? a2 : -1e30f;
        a3 = valid ? a3 : -1e30f;
        float sred = (__expf(a0) + __expf(a1)) + (__expf(a2) + __expf(a3));
        sred = group16_sum(sred);
        if (((lane & 15) == 15) && valid) atomicAdd(dst + i, sred);
      }
    }
  } else {
    const int i = 1535 - bid;   // 1023..1
    int   ai = actions[i];
    float av = action_logps[((size_t)i * B_N + lane) * A_N + ai];

    // two independent online-softmax chains (halved dependent latency)
    float mA = -1e30f, aA = 0.f, mB = -1e30f, aB = 0.f;
    for (int jj = wv; jj <= i; jj += 8) {
      float u0 = u_ws[jj * B_N + lane];
      int   j1 = jj + 4;
      float u1 = (j1 <= i) ? u_ws[j1 * B_N + lane] : -1e30f;
      float n0 = fmaxf(mA, u0);
      aA = aA * __expf(mA - n0) + __expf(u0 - n0);
      mA = n0;
      float n1 = fmaxf(mB, u1);
      aB = aB * __expf(mB - n1) + __expf(u1 - n1);
      mB = n1;
    }
    float m   = fmaxf(mA, mB);
    float acc = aA * __expf(mA - m) + aB * __expf(mB - m);

    sm[wv][lane] = m; sa[wv][lane] = acc;
    __syncthreads();
    if (wv == 0) {
      float m0 = sm[0][lane], m1 = sm[1][lane], m2 = sm[2][lane], m3 = sm[3][lane];
      float M2 = fmaxf(fmaxf(m0, m1), fmaxf(m2, m3));
      float A  = sa[0][lane] * __expf(m0 - M2) + sa[1][lane] * __expf(m1 - M2)
               + sa[2][lane] * __expf(m2 - M2) + sa[3][lane] * __expf(m3 - M2);
      float S  = M2 + __logf(A);
      float val = S + D_ws[(size_t)i * B_N + lane] + av;
      float mx  = wave_max64(val);
      float sum = wave_sum64(__expf(val - mx));
      if (lane == 0) LQ[i] = mx + __logf(sum);
    }
  }
}

// =============== K5: combine ===============
__global__ __launch_bounds__(256) void finish_kernel(
    const float* __restrict__ A1p,
    const float* __restrict__ LQ,
    float* __restrict__ out)
{
  const int i = (int)blockIdx.x * 256 + (int)threadIdx.x;   // grid 4
  float v = 0.f;
  if (i >= 1 && i <= 1023) {
    float a = 0.f;
    #pragma unroll 8
    for (int p = 0; p < 64; ++p) a += A1p[(p << 10) + i];
    v = __logf(a) - LQ[i];
  }
  float ws = wave_sum64(v);
  __shared__ float sb[4];
  if ((threadIdx.x & 63) == 0) sb[threadIdx.x >> 6] = ws;
  __syncthreads();
  if (threadIdx.x == 0) atomicAdd(out, sb[0] + sb[1] + sb[2] + sb[3]);
}

extern "C" void kernel_launch(void* const* d_in, const int* in_sizes, int n_in,
                              void* d_out, int out_size, void* d_ws, size_t ws_size,
                              hipStream_t stream) {
  const int*   actions      = (const int*)d_in[0];
  const float* action_logps = (const float*)d_in[1];
  const float* stop_logps   = (const float*)d_in[2];
  const float* start_logps  = (const float*)d_in[3];
  const float* cons_pen     = (const float*)d_in[4];
  float* out = (float*)d_out;

  float* z_ws  = (float*)d_ws;                  // 1024*64 (only rows 32w used)
  float* u_ws  = z_ws + T_N * B_N;              // 1024*64
  float* D_ws  = u_ws + T_N * B_N;              // 1024*64
  float* A1p   = D_ws + T_N * B_N;              // 64*1024
  float* r_ws  = A1p + 64 * 1024;               // 1024 (16B aligned)
  float* wexp  = r_ws + T_N;                    // 64
  float* LQ    = wexp + 64;                     // 1024
  float* cs32  = LQ + T_N;                      // 32*64
  float* quadQ = cs32 + 32 * B_N;               // 256*4*64*4 floats (16B aligned)

  hipLaunchKernelGGL(prep_kernel, dim3(256), dim3(64), 0, stream,
                     stop_logps, start_logps, quadQ, cs32, A1p);
  hipLaunchKernelGGL(scan_kernel, dim3(1), dim3(64), 0, stream,
                     stop_logps, start_logps, quadQ, z_ws, r_ws, wexp);
  hipLaunchKernelGGL(post_kernel, dim3(32), dim3(64), 0, stream,
                     actions, action_logps, stop_logps, start_logps,
                     z_ws, r_ws, wexp, cs32, u_ws, D_ws, out);
  hipLaunchKernelGGL(cons_logp_kernel, dim3(1535), dim3(256), 0, stream,
                     cons_pen, u_ws, D_ws, actions, action_logps, A1p, LQ);
  hipLaunchKernelGGL(finish_kernel, dim3(4), dim3(256), 0, stream,
                     A1p, LQ, out);
}

// Round 7
// 449.572 us; speedup vs baseline: 1.1278x; 1.0304x over previous
//
#include <hip/hip_runtime.h>

#define T_N 1024
#define B_N 64
#define A_N 128
#define TP1 1025
// STOP_IX=0, CONT_IX=1, ABSTRACT_PENALTY=0.5, CONSISTENCY_RATIO=1.0

typedef float f32x4 __attribute__((ext_vector_type(4)));

__device__ __forceinline__ float bcf(int x){ return __builtin_bit_cast(float, x); }
__device__ __forceinline__ int   bci(float x){ return __builtin_bit_cast(int, x); }

// ---- DPP helpers ----
template<int CTRL, int RM>
__device__ __forceinline__ float dpp_add_step(float x){
  int t = __builtin_amdgcn_update_dpp(0, bci(x), CTRL, RM, 0xf, true);
  return x + bcf(t);
}
__device__ __forceinline__ float wave_sum64(float x){
  x = dpp_add_step<0x111,0xf>(x);   // row_shr:1
  x = dpp_add_step<0x112,0xf>(x);   // row_shr:2
  x = dpp_add_step<0x114,0xf>(x);   // row_shr:4
  x = dpp_add_step<0x118,0xf>(x);   // row_shr:8
  x = dpp_add_step<0x142,0xa>(x);   // row_bcast15
  x = dpp_add_step<0x143,0xc>(x);   // row_bcast31; lane63 = total
  return bcf(__builtin_amdgcn_readlane(bci(x), 63));
}
// four interleaved reductions: ~1 chain latency for 4 sums
__device__ __forceinline__ void wave_sum64_x4(float a, float b, float c, float d,
                                              float& ra, float& rb, float& rc, float& rd){
  a = dpp_add_step<0x111,0xf>(a); b = dpp_add_step<0x111,0xf>(b);
  c = dpp_add_step<0x111,0xf>(c); d = dpp_add_step<0x111,0xf>(d);
  a = dpp_add_step<0x112,0xf>(a); b = dpp_add_step<0x112,0xf>(b);
  c = dpp_add_step<0x112,0xf>(c); d = dpp_add_step<0x112,0xf>(d);
  a = dpp_add_step<0x114,0xf>(a); b = dpp_add_step<0x114,0xf>(b);
  c = dpp_add_step<0x114,0xf>(c); d = dpp_add_step<0x114,0xf>(d);
  a = dpp_add_step<0x118,0xf>(a); b = dpp_add_step<0x118,0xf>(b);
  c = dpp_add_step<0x118,0xf>(c); d = dpp_add_step<0x118,0xf>(d);
  a = dpp_add_step<0x142,0xa>(a); b = dpp_add_step<0x142,0xa>(b);
  c = dpp_add_step<0x142,0xa>(c); d = dpp_add_step<0x142,0xa>(d);
  a = dpp_add_step<0x143,0xc>(a); b = dpp_add_step<0x143,0xc>(b);
  c = dpp_add_step<0x143,0xc>(c); d = dpp_add_step<0x143,0xc>(d);
  ra = bcf(__builtin_amdgcn_readlane(bci(a), 63));
  rb = bcf(__builtin_amdgcn_readlane(bci(b), 63));
  rc = bcf(__builtin_amdgcn_readlane(bci(c), 63));
  rd = bcf(__builtin_amdgcn_readlane(bci(d), 63));
}
__device__ __forceinline__ float group16_sum(float x){
  x = dpp_add_step<0x111,0xf>(x);
  x = dpp_add_step<0x112,0xf>(x);
  x = dpp_add_step<0x114,0xf>(x);
  x = dpp_add_step<0x118,0xf>(x);
  return x;                          // lane 15 of each 16-group has group sum
}
template<int CTRL, int RM>
__device__ __forceinline__ float dpp_max_step(float x){
  int t = __builtin_amdgcn_update_dpp(bci(-3.4e38f), bci(x), CTRL, RM, 0xf, false);
  return fmaxf(x, bcf(t));
}
__device__ __forceinline__ float wave_max64(float x){
  x = dpp_max_step<0x111,0xf>(x);
  x = dpp_max_step<0x112,0xf>(x);
  x = dpp_max_step<0x114,0xf>(x);
  x = dpp_max_step<0x118,0xf>(x);
  x = dpp_max_step<0x142,0xa>(x);
  x = dpp_max_step<0x143,0xc>(x);
  return bcf(__builtin_amdgcn_readlane(bci(x), 63));
}

// =============== K0: prep, 256 blocks x 64 (1 quad/wave) ===============
// Quad p covers steps i = 4p+1 .. 4p+4 (p = 0..254). Slots:
//   s0 = {V1,V2,V3,V4}     dot vectors V_k = e_k * prod_{m<k} c_m
//   s1 = {Cq,T1,T2,T3}     z4 = Cq z0 + T1 d1 + T2 d2 + T3 d3 + T4 d4
//   s2 = {T4,m21,m31,m32}  r = M d (lower-tri, lane-uniform m's; post uses these)
//   s3 = {m41,m42,m43,0}
// Also zeros A1p and computes 16-step cont chunk sums cs16[64][64].
__global__ __launch_bounds__(64) void prep_kernel(
    const float* __restrict__ stop_logps,
    const float* __restrict__ start_logps,
    float* __restrict__ quadQ,   // [256][4][64][4] (quad 255 = dummy)
    float* __restrict__ cs16,    // [64][64]
    float* __restrict__ A1p)     // 64*1024, zeroed here
{
  const int bid  = (int)blockIdx.x;   // 0..255
  const int lane = (int)threadIdx.x;
  const float KAPPA = 0.60653065971263342f;    // e^-0.5
  const float2* stop2 = (const float2*)stop_logps;

  // zero A1p: 65536 floats / 16384 threads = 4 each
  int g = bid * 64 + lane;
  A1p[g] = 0.f; A1p[g + 16384] = 0.f; A1p[g + 32768] = 0.f; A1p[g + 49152] = 0.f;

  if (bid < 255) {
    const int i1 = 4 * bid + 1;
    float2 q1 = stop2[(i1 + 0) * B_N + lane];
    float2 q2 = stop2[(i1 + 1) * B_N + lane];
    float2 q3 = stop2[(i1 + 2) * B_N + lane];
    float2 q4 = stop2[(i1 + 3) * B_N + lane];
    float t1 = start_logps[(i1 + 0) * B_N + lane];
    float t2 = start_logps[(i1 + 1) * B_N + lane];
    float t3 = start_logps[(i1 + 2) * B_N + lane];
    float t4 = start_logps[(i1 + 3) * B_N + lane];
    float e1 = __expf(q1.x), c1 = __expf(q1.y), s1 = KAPPA * __expf(t1);
    float e2 = __expf(q2.x), c2 = __expf(q2.y), s2 = KAPPA * __expf(t2);
    float e3 = __expf(q3.x), c3 = __expf(q3.y), s3 = KAPPA * __expf(t3);
    float e4 = __expf(q4.x), c4 = __expf(q4.y), s4 = KAPPA * __expf(t4);

    float c21  = c2 * c1;
    float c321 = c3 * c21;
    float V1 = e1;
    float V2 = e2 * c1;
    float V3 = e3 * c21;
    float V4 = e4 * c321;

    float Cq = c4 * c321;
    float S1 = c4 * c3 * c2 * s1;
    float S2 = c4 * c3 * s2;
    float S3 = c4 * s3;
    float S4 = s4;

    float k21 = wave_sum64(e2 * s1);
    float k31 = wave_sum64(e3 * c2 * s1);
    float k32 = wave_sum64(e3 * s2);
    float k41 = wave_sum64(e4 * c3 * c2 * s1);
    float k42 = wave_sum64(e4 * c3 * s2);
    float k43 = wave_sum64(e4 * s3);

    float m21 = k21, m32 = k32, m43 = k43;
    float m31 = __builtin_fmaf(k32, k21, k31);
    float m42 = __builtin_fmaf(k43, k32, k42);
    float m41 = __builtin_fmaf(k43, m31, __builtin_fmaf(k42, k21, k41));

    float T4 = S4;
    float T3 = __builtin_fmaf(S4, m43, S3);
    float T2 = __builtin_fmaf(S4, m42, __builtin_fmaf(S3, m32, S2));
    float T1 = __builtin_fmaf(S4, m41,
               __builtin_fmaf(S3, m31, __builtin_fmaf(S2, m21, S1)));

    f32x4* qs = (f32x4*)quadQ;
    size_t base = (size_t)bid * 4 * 64 + lane;
    qs[base + 0 * 64] = (f32x4){V1, V2, V3, V4};
    qs[base + 1 * 64] = (f32x4){Cq, T1, T2, T3};
    qs[base + 2 * 64] = (f32x4){T4, m21, m31, m32};
    qs[base + 3 * 64] = (f32x4){m41, m42, m43, 0.f};
  }

  // cont chunk sums at 16-granularity (chunk c = i in [16c+1, 16c+16])
  if (bid < 64) {
    float s = 0.f;
    for (int k = 1; k <= 16; ++k) {
      int i = 16 * bid + k;
      if (i <= 1023) s += stop2[i * B_N + lane].y;
    }
    cs16[bid * B_N + lane] = s;
  }
}

// =============== K1: serial scan (block 0) + cons_pen L3-prefetch (blocks 1..255) ===============
// Block 0, threads 0..63: quad-step scan. Per quad: 3 packed loads, 4 muls,
// 4 interleaved DPP reductions, 5-fma z4 jump, d-store (r-solve moved to post).
// Boundary z rows stored POST-rescale at every 16-multiple (rows 16..992,1008).
// Window rescale at (q&3)==3, exponent of d4 (self-consistent via wexp).
// d_ws[i-1] = raw dot d at step i (tail singles store r directly).
// Blocks 1..255: stream cons_pen row-pair (j=bid-1, 1023-(bid-1)) through the
// cache hierarchy (Infinity Cache prefetch) while the serial scan runs.
// 64 KB dynamic LDS caps co-residency at 2 blocks/CU so prefetch spreads out.
__global__ __launch_bounds__(256, 1) void scan_kernel(
    const float* __restrict__ stop_logps,
    const float* __restrict__ start_logps,
    const float* __restrict__ quadQ,
    const float* __restrict__ cons_pen,
    float* __restrict__ z_ws,     // rows 16m (m=1..63) only, post-rescale
    float* __restrict__ d_ws,     // 1024; d_ws[i-1] = d at step i
    float* __restrict__ wexp,     // 64 (0..62 used)
    float* __restrict__ sink)     // 256 floats (prefetch DCE sink)
{
  extern __shared__ float lds_pad[];   // sized at launch (occupancy cap only)
  (void)lds_pad;
  const int bid = (int)blockIdx.x;

  if (bid != 0) {
    // ---- prefetch pair c = bid-1 (rows j and 1023-j) into L3 ----
    const int c = bid - 1;                    // 0..254
    float s = 0.f;
    #pragma unroll
    for (int t = 0; t < 2; ++t) {
      const int j = t ? (1023 - c) : c;
      const f32x4* p4 = (const f32x4*)(cons_pen + ((size_t)j * TP1 + j) * B_N);
      const int n4 = (1024 - j) * 16;         // f32x4 count in the row span
      for (int base = 0; base < n4; base += 256 * 8) {
        #pragma unroll
        for (int u = 0; u < 8; ++u) {
          int idx = base + (int)threadIdx.x + 256 * u;
          if (idx < n4) s += p4[idx].x;
        }
      }
    }
    sink[bid] = s;                            // keep loads alive
    return;
  }
  if (threadIdx.x >= 64) return;

  const int lane = (int)threadIdx.x;
  const float2* stop2 = (const float2*)stop_logps;

  // prefetch tail-single coefficients (steps 1021..1023) now
  float2 sct0 = stop2[1021 * B_N + lane];
  float2 sct1 = stop2[1022 * B_N + lane];
  float2 sct2 = stop2[1023 * B_N + lane];
  float stt0 = start_logps[1021 * B_N + lane];
  float stt1 = start_logps[1022 * B_N + lane];
  float stt2 = start_logps[1023 * B_N + lane];

  float z = __expf(start_logps[lane]);   // y_0, scale P=0

  const f32x4* qs = (const f32x4*)quadQ;

  // 8-quad (32-step) rotating prefetch; slot 3 (m4x) not needed by the scan
  f32x4 qb[8][3];
  #pragma unroll
  for (int q = 0; q < 8; ++q)
    #pragma unroll
    for (int s = 0; s < 3; ++s)
      qb[q][s] = qs[((size_t)q * 4 + s) * 64 + lane];

  for (int p0 = 0; p0 < 248; p0 += 8) {
    #pragma unroll
    for (int q = 0; q < 8; ++q) {
      const int p = p0 + q;
      f32x4 V = qb[q][0];
      f32x4 Z = qb[q][1];   // {Cq,T1,T2,T3}
      f32x4 W = qb[q][2];   // {T4,-,-,-}
      // prefetch quad p+8 (quad 255 is a dummy slot, loaded but never used)
      {
        const int pn = p + 8;
        #pragma unroll
        for (int s = 0; s < 3; ++s)
          qb[q][s] = qs[((size_t)pn * 4 + s) * 64 + lane];
      }

      float d1, d2, d3, d4;
      wave_sum64_x4(z * V.x, z * V.y, z * V.z, z * V.w, d1, d2, d3, d4);
      if (lane == 0) *(f32x4*)(d_ws + 4 * p) = (f32x4){d1, d2, d3, d4};

      // z4 jump directly from d's (depth-3 tree)
      float p1 = __builtin_fmaf(d2, Z.z, __builtin_fmaf(d1, Z.y, z * Z.x));
      float p2 = __builtin_fmaf(d4, W.x, d3 * Z.w);
      z = p1 + p2;

      if ((q & 3) == 3) {                 // step 16m+16: window boundary
        int e16 = ((bci(d4) >> 23) & 255) - 127;
        z = ldexpf(z, -e16);
        if (lane == 0) wexp[p >> 2] = (float)e16;
        z_ws[(4 * p + 4) * B_N + lane] = z;   // post-rescale boundary row
      }
    }
  }
  // tail quads 248..254 (steps 993..1020); rescale+store only at p==251 (step 1008)
  #pragma unroll
  for (int q = 0; q < 7; ++q) {
    const int p = 248 + q;
    f32x4 V = qb[q][0];
    f32x4 Z = qb[q][1];
    f32x4 W = qb[q][2];
    float d1, d2, d3, d4;
    wave_sum64_x4(z * V.x, z * V.y, z * V.z, z * V.w, d1, d2, d3, d4);
    if (lane == 0) *(f32x4*)(d_ws + 4 * p) = (f32x4){d1, d2, d3, d4};
    float p1 = __builtin_fmaf(d2, Z.z, __builtin_fmaf(d1, Z.y, z * Z.x));
    float p2 = __builtin_fmaf(d4, W.x, d3 * Z.w);
    z = p1 + p2;
    if (q == 3) {                         // p==251, step 1008 boundary
      int e16 = ((bci(d4) >> 23) & 255) - 127;
      z = ldexpf(z, -e16);
      if (lane == 0) wexp[62] = (float)e16;
      z_ws[1008 * B_N + lane] = z;
    }
  }
  // singles: steps 1021..1023 (window 63, no rescale; store r directly)
  const float KAPPA = 0.60653065971263342f;
  {
    float esw = __expf(sct0.x), ecw = __expf(sct0.y), sv = KAPPA * __expf(stt0);
    float r = wave_sum64(z * esw);
    z = __builtin_fmaf(sv, r, z * ecw);
    if (lane == 0) d_ws[1020] = r;
  }
  {
    float esw = __expf(sct1.x), ecw = __expf(sct1.y), sv = KAPPA * __expf(stt1);
    float r = wave_sum64(z * esw);
    z = __builtin_fmaf(sv, r, z * ecw);
    if (lane == 0) d_ws[1021] = r;
  }
  {
    float esw = __expf(sct2.x), ecw = __expf(sct2.y), sv = KAPPA * __expf(stt2);
    float r = wave_sum64(z * esw);
    z = __builtin_fmaf(sv, r, z * ecw);
    if (lane == 0) d_ws[1022] = r;
  }
}

// =============== K2: bookkeeping, 64 parallel blocks (1 wave each) ===============
// Block w handles i in [16w+1, min(16w+16,1023)] — exactly one scale window,
// so no in-chunk rescale. Entry z = z_ws[16w] (post-rescale, window-w scale).
// Reconstructs r from raw d's using the quadQ m-couplings (same fma order as
// the old scan solve -> bit-identical r).
__global__ __launch_bounds__(64) void post_kernel(
    const int* __restrict__ actions,
    const float* __restrict__ action_logps,
    const float* __restrict__ stop_logps,
    const float* __restrict__ start_logps,
    const float* __restrict__ quadQ,
    const float* __restrict__ z_ws,
    const float* __restrict__ d_ws,
    const float* __restrict__ wexp,
    const float* __restrict__ cs16,
    float* __restrict__ u_ws,
    float* __restrict__ D_ws,
    float* __restrict__ out)
{
  const int w    = (int)blockIdx.x;   // 0..63
  const int lane = (int)threadIdx.x;  // = b
  const float LN2   = 0.69314718055994531f;
  const float KAPPA = 0.60653065971263342f;
  const float2* stop2 = (const float2*)stop_logps;
  const f32x4* qs = (const f32x4*)quadQ;

  float wl = (lane < 63) ? wexp[lane] : 0.f;

  // window-scale prefix entering window w
  float Pv = LN2 * wave_sum64((lane < w) ? wl : 0.f);

  // cont-logp prefix entering the chunk
  float C = 0.f;
  for (int c = 0; c < w; ++c) C += cs16[c * B_N + lane];

  // chunk-entry z (window-w scale)
  float z;
  if (w == 0) {
    z = __expf(start_logps[lane]);
    u_ws[lane] = start_logps[lane];       // u_0 = st0
  } else {
    z = z_ws[(16 * w) * B_N + lane];      // stored post-rescale by the scan
  }

  const int nquad = (w == 63) ? 3 : 4;    // w=63: quads 252..254 then 3 singles
  for (int g = 0; g < nquad; ++g) {
    const int gq = 4 * w + g;             // global quad index
    f32x4 Wm = qs[((size_t)gq * 4 + 2) * 64 + lane];  // {T4,m21,m31,m32}
    f32x4 Xm = qs[((size_t)gq * 4 + 3) * 64 + lane];  // {m41,m42,m43,-}
    f32x4 dv = *(const f32x4*)(d_ws + 4 * gq);
    float r0 = dv.x;
    float r1 = __builtin_fmaf(Wm.y, dv.x, dv.y);
    float r2 = __builtin_fmaf(Wm.w, dv.y, __builtin_fmaf(Wm.z, dv.x, dv.z));
    float r3 = __builtin_fmaf(Xm.z, dv.z,
               __builtin_fmaf(Xm.y, dv.y, __builtin_fmaf(Xm.x, dv.x, dv.w)));
    float rq[4] = {r0, r1, r2, r3};
    #pragma unroll
    for (int k2 = 0; k2 < 4; ++k2) {
      int i = 4 * gq + k2 + 1;
      float cont = stop2[i * B_N + lane].y;
      float stv  = start_logps[i * B_N + lane];
      float r    = rq[k2];
      C += cont;
      float ecw = __expf(cont);
      float sv  = KAPPA * __expf(stv);
      z = __builtin_fmaf(r, sv, ecw * z);
      float zs = wave_sum64(z);
      float R  = __logf(r) + Pv - 0.5f;
      u_ws[i * B_N + lane] = stv + R - C;
      D_ws[i * B_N + lane] = C - (__logf(zs) + Pv);
    }
  }
  if (w == 63) {                          // singles: steps 1021..1023 (r stored)
    #pragma unroll
    for (int k2 = 0; k2 < 3; ++k2) {
      int i = 1021 + k2;
      float cont = stop2[i * B_N + lane].y;
      float stv  = start_logps[i * B_N + lane];
      float r    = d_ws[i - 1];           // already r for singles
      C += cont;
      float ecw = __expf(cont);
      float sv  = KAPPA * __expf(stv);
      z = __builtin_fmaf(r, sv, ecw * z);
      float zs = wave_sum64(z);
      float R  = __logf(r) + Pv - 0.5f;
      u_ws[i * B_N + lane] = stv + R - C;
      D_ws[i * B_N + lane] = C - (__logf(zs) + Pv);
    }
    // z = z_1023 (window-63 scale), Pv = P(63)
    float st0 = start_logps[lane];
    int   a0  = actions[0];
    float al0 = action_logps[lane * A_N + a0];
    float lp0 = __logf(wave_sum64(__expf(st0 + al0)));
    float stopT = stop_logps[(T_N * B_N + lane) * 2 + 0];
    float fin = __logf(wave_sum64(z * __expf(stopT))) + Pv;
    if (lane == 0) out[0] = -(lp0 + fin);
  }
}

// =============== K34: fused consistency + logp ===============
// blocks 0..511   : cons rows j = bid and 1023-bid (constant 1025 rows/block)
// blocks 512..1534: logp term for i = 1535-bid (1023..1, longest first)
// Plain (cache-allocating) loads so the scan-phase L3 prefetch pays off.
__global__ __launch_bounds__(256) void cons_logp_kernel(
    const float* __restrict__ cons_pen,
    const float* __restrict__ u_ws,
    const float* __restrict__ D_ws,
    const int* __restrict__ actions,
    const float* __restrict__ action_logps,
    float* __restrict__ A1p,
    float* __restrict__ LQ)
{
  const int bid  = (int)blockIdx.x;
  const int tid  = (int)threadIdx.x;
  const int lane = tid & 63;
  const int wv   = tid >> 6;

  __shared__ float sm[4][64];
  __shared__ float sa[4][64];

  if (bid < 512) {
    const int bq  = (lane & 15) * 4;
    const int row = lane >> 4;
    #pragma unroll
    for (int t = 0; t < 2; ++t) {
      const int j = t ? (1023 - bid) : bid;
      const float4 u4 = *(const float4*)(u_ws + j * B_N + bq);
      float* dst = A1p + ((j & 63) << 10);
      for (int i0 = j + 4 * wv; i0 <= 1023; i0 += 16) {
        int i  = i0 + row;
        int iL = i > 1023 ? 1023 : i;
        f32x4 cp4 = *(const f32x4*)(cons_pen + ((size_t)j * TP1 + iL) * B_N + bq);
        float4 d4  = *(const float4*)(D_ws + (size_t)iL * B_N + bq);
        bool valid = (i >= 1) && (i <= 1023);
        float a0 = u4.x + d4.x + cp4.x;
        float a1 = u4.y + d4.y + cp4.y;
        float a2 = u4.z + d4.z + cp4.z;
        float a3 = u4.w + d4.w + cp4.w;
        a0 = valid ? a0 : -1e30f;
        a1 = valid ? a1 : -1e30f;
        a2 = valid ? a2 : -1e30f;
        a3 = valid ? a3 : -1e30f;
        float sred = (__expf(a0) + __expf(a1)) + (__expf(a2) + __expf(a3));
        sred = group16_sum(sred);
        if (((lane & 15) == 15) && valid) atomicAdd(dst + i, sred);
      }
    }
  } else {
    const int i = 1535 - bid;   // 1023..1
    int   ai = actions[i];
    float av = action_logps[((size_t)i * B_N + lane) * A_N + ai];

    // two independent online-softmax chains (halved dependent latency)
    float mA = -1e30f, aA = 0.f, mB = -1e30f, aB = 0.f;
    for (int jj = wv; jj <= i; jj += 8) {
      float u0 = u_ws[jj * B_N + lane];
      int   j1 = jj + 4;
      float u1 = (j1 <= i) ? u_ws[j1 * B_N + lane] : -1e30f;
      float n0 = fmaxf(mA, u0);
      aA = aA * __expf(mA - n0) + __expf(u0 - n0);
      mA = n0;
      float n1 = fmaxf(mB, u1);
      aB = aB * __expf(mB - n1) + __expf(u1 - n1);
      mB = n1;
    }
    float m   = fmaxf(mA, mB);
    float acc = aA * __expf(mA - m) + aB * __expf(mB - m);

    sm[wv][lane] = m; sa[wv][lane] = acc;
    __syncthreads();
    if (wv == 0) {
      float m0 = sm[0][lane], m1 = sm[1][lane], m2 = sm[2][lane], m3 = sm[3][lane];
      float M2 = fmaxf(fmaxf(m0, m1), fmaxf(m2, m3));
      float A  = sa[0][lane] * __expf(m0 - M2) + sa[1][lane] * __expf(m1 - M2)
               + sa[2][lane] * __expf(m2 - M2) + sa[3][lane] * __expf(m3 - M2);
      float S  = M2 + __logf(A);
      float val = S + D_ws[(size_t)i * B_N + lane] + av;
      float mx  = wave_max64(val);
      float sum = wave_sum64(__expf(val - mx));
      if (lane == 0) LQ[i] = mx + __logf(sum);
    }
  }
}

// =============== K5: combine ===============
__global__ __launch_bounds__(256) void finish_kernel(
    const float* __restrict__ A1p,
    const float* __restrict__ LQ,
    float* __restrict__ out)
{
  const int i = (int)blockIdx.x * 256 + (int)threadIdx.x;   // grid 4
  float v = 0.f;
  if (i >= 1 && i <= 1023) {
    float a = 0.f;
    #pragma unroll 8
    for (int p = 0; p < 64; ++p) a += A1p[(p << 10) + i];
    v = __logf(a) - LQ[i];
  }
  float ws = wave_sum64(v);
  __shared__ float sb[4];
  if ((threadIdx.x & 63) == 0) sb[threadIdx.x >> 6] = ws;
  __syncthreads();
  if (threadIdx.x == 0) atomicAdd(out, sb[0] + sb[1] + sb[2] + sb[3]);
}

extern "C" void kernel_launch(void* const* d_in, const int* in_sizes, int n_in,
                              void* d_out, int out_size, void* d_ws, size_t ws_size,
                              hipStream_t stream) {
  const int*   actions      = (const int*)d_in[0];
  const float* action_logps = (const float*)d_in[1];
  const float* stop_logps   = (const float*)d_in[2];
  const float* start_logps  = (const float*)d_in[3];
  const float* cons_pen     = (const float*)d_in[4];
  float* out = (float*)d_out;

  float* z_ws  = (float*)d_ws;                  // 1024*64 (only rows 16m used)
  float* u_ws  = z_ws + T_N * B_N;              // 1024*64
  float* D_ws  = u_ws + T_N * B_N;              // 1024*64
  float* A1p   = D_ws + T_N * B_N;              // 64*1024
  float* d_wsv = A1p + 64 * 1024;               // 1024 (16B aligned)
  float* wexp  = d_wsv + T_N;                   // 64
  float* LQ    = wexp + 64;                     // 1024
  float* cs16  = LQ + T_N;                      // 64*64
  float* quadQ = cs16 + 64 * B_N;               // 256*4*64*4 floats (16B aligned)
  float* sink  = quadQ + 256 * 4 * B_N * 4;     // 256 floats, past quadQ end

  hipLaunchKernelGGL(prep_kernel, dim3(256), dim3(64), 0, stream,
                     stop_logps, start_logps, quadQ, cs16, A1p);
  hipLaunchKernelGGL(scan_kernel, dim3(256), dim3(256), 65536, stream,
                     stop_logps, start_logps, quadQ, cons_pen,
                     z_ws, d_wsv, wexp, sink);
  hipLaunchKernelGGL(post_kernel, dim3(64), dim3(64), 0, stream,
                     actions, action_logps, stop_logps, start_logps,
                     quadQ, z_ws, d_wsv, wexp, cs16, u_ws, D_ws, out);
  hipLaunchKernelGGL(cons_logp_kernel, dim3(1535), dim3(256), 0, stream,
                     cons_pen, u_ws, D_ws, actions, action_logps, A1p, LQ);
  hipLaunchKernelGGL(finish_kernel, dim3(4), dim3(256), 0, stream,
                     A1p, LQ, out);
}